// Round 1
// 491.244 us; speedup vs baseline: 1.4513x; 1.4513x over previous
//
#include <hip/hip_runtime.h>
#include <math.h>

// Problem constants: S=512, B=256, V=100000, E=128, H=256
#define S_LEN 512
#define B_SZ  256
#define E_SZ  128
#define H_SZ  256

typedef __attribute__((ext_vector_type(8))) short bf16x8;
typedef __attribute__((ext_vector_type(4))) short bf16x4;
typedef __attribute__((ext_vector_type(4))) float f32x4;

__device__ __forceinline__ short f2bf(float f) {
    union { float f; unsigned u; } v; v.f = f;
    unsigned r = v.u + 0x7FFFu + ((v.u >> 16) & 1u);   // RNE
    return (short)(r >> 16);
}

// tanh(v) = 1 - 2/(exp(2v)+1); v_rcp_f32 (~1 ulp) is far below bf16 state noise.
__device__ __forceinline__ float tanh_fast(float v) {
    float e = __expf(2.f * v);
    return 1.f - 2.f * __builtin_amdgcn_rcpf(e + 1.f);
}

// ---------------------------------------------------------------------------
// Kernel 1: embedding gather + input projection, fp32 LDS-tiled GEMM.
// (unchanged this round; ~179 us, later target)
// ---------------------------------------------------------------------------
#define K1_ROWS 64
#define K1_KP   32
#define K1_AP   (K1_ROWS + 4)
#define K1_WP   (H_SZ + 4)

__global__ __launch_bounds__(256) void embed_proj_kernel(
    const int*   __restrict__ X,
    const float* __restrict__ emb,
    const float* __restrict__ W_ih,
    const float* __restrict__ b_ih,
    const float* __restrict__ b_hh,
    float*       __restrict__ xproj)
{
    __shared__ int   toks[K1_ROWS];
    __shared__ float A_lds[K1_KP][K1_AP];
    __shared__ float W_lds[K1_KP][K1_WP];

    const int tid  = threadIdx.x;
    const int row0 = blockIdx.x * K1_ROWS;

    if (tid < K1_ROWS) toks[tid] = X[row0 + tid];

    const int r0 = (tid & 7) * 8;
    const int h0 = (tid >> 3) * 8;

    float acc[8][8];
#pragma unroll
    for (int i = 0; i < 8; ++i)
#pragma unroll
        for (int j = 0; j < 8; ++j) acc[i][j] = 0.f;

    __syncthreads();

    const int ar = tid >> 2;
    const int ak = (tid & 3) * 8;

#pragma unroll
    for (int p = 0; p < E_SZ / K1_KP; ++p) {
        {
            const float4* src = (const float4*)(emb + (size_t)toks[ar] * E_SZ + p * K1_KP + ak);
            float4 v0 = src[0], v1 = src[1];
            A_lds[ak+0][ar] = v0.x; A_lds[ak+1][ar] = v0.y;
            A_lds[ak+2][ar] = v0.z; A_lds[ak+3][ar] = v0.w;
            A_lds[ak+4][ar] = v1.x; A_lds[ak+5][ar] = v1.y;
            A_lds[ak+6][ar] = v1.z; A_lds[ak+7][ar] = v1.w;
        }
        {
            const float4* src = (const float4*)(W_ih + (size_t)tid * E_SZ + p * K1_KP);
#pragma unroll
            for (int j = 0; j < 8; ++j) {
                float4 v = src[j];
                W_lds[j*4+0][tid] = v.x; W_lds[j*4+1][tid] = v.y;
                W_lds[j*4+2][tid] = v.z; W_lds[j*4+3][tid] = v.w;
            }
        }
        __syncthreads();

#pragma unroll 4
        for (int k = 0; k < K1_KP; ++k) {
            const float4 a0 = *(const float4*)&A_lds[k][r0];
            const float4 a1 = *(const float4*)&A_lds[k][r0 + 4];
            const float4 w0 = *(const float4*)&W_lds[k][h0];
            const float4 w1 = *(const float4*)&W_lds[k][h0 + 4];
            const float av[8] = {a0.x,a0.y,a0.z,a0.w,a1.x,a1.y,a1.z,a1.w};
            const float wv[8] = {w0.x,w0.y,w0.z,w0.w,w1.x,w1.y,w1.z,w1.w};
#pragma unroll
            for (int i = 0; i < 8; ++i)
#pragma unroll
                for (int j = 0; j < 8; ++j)
                    acc[i][j] += av[i] * wv[j];
        }
        __syncthreads();
    }

    float bias[8];
#pragma unroll
    for (int j = 0; j < 8; ++j) bias[j] = b_ih[h0 + j] + b_hh[h0 + j];

#pragma unroll
    for (int i = 0; i < 8; ++i) {
        const size_t row = (size_t)(row0 + r0 + i);
        float4 o0, o1;
        o0.x = acc[i][0] + bias[0]; o0.y = acc[i][1] + bias[1];
        o0.z = acc[i][2] + bias[2]; o0.w = acc[i][3] + bias[3];
        o1.x = acc[i][4] + bias[4]; o1.y = acc[i][5] + bias[5];
        o1.z = acc[i][6] + bias[6]; o1.w = acc[i][7] + bias[7];
        *(float4*)&xproj[row * H_SZ + h0]     = o0;
        *(float4*)&xproj[row * H_SZ + h0 + 4] = o1;
    }
}

// ---------------------------------------------------------------------------
// Kernel 2: MFMA recurrent scan + log_softmax.  v2:
//  - 512 threads (8 waves, 2 waves/SIMD) -> latency overlap; wave owns 2
//    m-tiles (32 h_out), 16 MFMAs/step as 4 independent chains of 4.
//  - State LDS in B-fragment-linear layout: buf[kk][lane'][8] where
//    lane' = quad*16+bl and buf[kk][l][j] = h[k = kk*32+(l>>4)*8+j] of batch
//    (l&15).  A wave's ds_read_b128 hits 64 contiguous 16B slots -> ZERO
//    bank conflicts (vs ~6 extra cyc/read before).
//  - tanh via v_rcp_f32 (kills the 10-inst exact-div sequence), state pack
//    via v_cvt_pk_bf16_f32 (2 insts vs ~8 manual RNE).
//  - Last iteration peeled (no per-step s==511 selects).
// ---------------------------------------------------------------------------
__global__ __launch_bounds__(512) void rnn_scan_kernel(
    const float* __restrict__ xproj,
    const float* __restrict__ W_hh,
    float*       __restrict__ out)
{
    const int tid  = threadIdx.x;
    const int wave = tid >> 6;      // 0..7
    const int lane = tid & 63;
    const int bl   = lane & 15;     // batch within block
    const int quad = lane >> 4;     // 0..3
    const int B0   = blockIdx.x * 16;

    __shared__ short HB[2][8][64][8];   // 2 x 8KB state buffers
    __shared__ float sred[8][16];

    // ---- A-operand: W_hh fragments, constant through the scan ----
    // lane holds A[m = (wave*2+mt)*16 + bl][k = kk*32 + quad*8 + j]
    bf16x8 wfrag[2][8];
#pragma unroll
    for (int mt = 0; mt < 2; ++mt) {
        const int h = wave * 32 + mt * 16 + bl;
#pragma unroll
        for (int kk = 0; kk < 8; ++kk) {
            const float* wp = W_hh + (size_t)h * H_SZ + kk * 32 + quad * 8;
            float4 x0 = *(const float4*)wp;
            float4 x1 = *(const float4*)(wp + 4);
            bf16x8 f;
            f[0] = f2bf(x0.x); f[1] = f2bf(x0.y); f[2] = f2bf(x0.z); f[3] = f2bf(x0.w);
            f[4] = f2bf(x1.x); f[5] = f2bf(x1.y); f[6] = f2bf(x1.z); f[7] = f2bf(x1.w);
            wfrag[mt][kk] = f;
        }
    }

    short* const hb0 = &HB[0][0][0][0];
    short* const hb1 = &HB[1][0][0][0];

    // zero initial state (buf 0): 512 threads x 16 B = 8192 B exactly
    ((int4*)hb0)[tid] = make_int4(0, 0, 0, 0);

    // read base: lane's 8 fragments at  kk*1024B + lane*16B
    const short* rd0 = hb0 + lane * 8;
    const short* rd1 = hb1 + lane * 8;

    // write slots: value for (h = wave*32 + mt*16 + quad*4 + r, batch bl) goes to
    // shorts offset (h>>5)*512 + ((h>>3)&3)*128 + bl*8 + (h&7)
    //   h>>5 = wave,  (h>>3)&3 = mt*2 + (quad>>1),  h&7 = (quad&1)*4 + r
    const int wo0 = wave * 512 + (quad >> 1) * 128 + bl * 8 + (quad & 1) * 4;
    const int wo1 = wo0 + 256;                       // mt=1: +2*128
    short* w0a = hb0 + wo0; short* w0b = hb0 + wo1;
    short* w1a = hb1 + wo0; short* w1b = hb1 + wo1;

    // xp pointers for this lane (xproj is LLC-resident: 134MB < 256MB L3)
    const float* xpb = xproj + (size_t)(B0 + bl) * H_SZ + wave * 32 + quad * 4;
    f32x4 xq0 = *(const f32x4*)xpb;
    f32x4 xq1 = *(const f32x4*)(xpb + 16);
    const float* xnp = xpb + (size_t)B_SZ * H_SZ;    // xp for step 1

    __syncthreads();

    auto do_step = [&](const short* rd, short* wa, short* wb) {
        // B-fragments: 8 x ds_read_b128, conflict-free contiguous
        bf16x8 bf[8];
#pragma unroll
        for (int kk = 0; kk < 8; ++kk)
            bf[kk] = *(const bf16x8*)(rd + kk * 512);

        // prefetch next step's xp (consumed next iteration -> latency hidden)
        f32x4 xn0 = *(const f32x4*)xnp;
        f32x4 xn1 = *(const f32x4*)(xnp + 16);
        xnp += (size_t)B_SZ * H_SZ;

        // 4 independent MFMA chains of 4 (2 m-tiles x 2 k-halves)
        f32x4 c0a = {0.f, 0.f, 0.f, 0.f}, c0b = {0.f, 0.f, 0.f, 0.f};
        f32x4 c1a = {0.f, 0.f, 0.f, 0.f}, c1b = {0.f, 0.f, 0.f, 0.f};
#pragma unroll
        for (int kk = 0; kk < 4; ++kk) {
            c0a = __builtin_amdgcn_mfma_f32_16x16x32_bf16(wfrag[0][kk],     bf[kk],     c0a, 0, 0, 0);
            c1a = __builtin_amdgcn_mfma_f32_16x16x32_bf16(wfrag[1][kk],     bf[kk],     c1a, 0, 0, 0);
            c0b = __builtin_amdgcn_mfma_f32_16x16x32_bf16(wfrag[0][kk + 4], bf[kk + 4], c0b, 0, 0, 0);
            c1b = __builtin_amdgcn_mfma_f32_16x16x32_bf16(wfrag[1][kk + 4], bf[kk + 4], c1b, 0, 0, 0);
        }
        const f32x4 d0 = c0a + c0b;
        const f32x4 d1 = c1a + c1b;

        // epilogue: v = D + xp, tanh, pack bf16, store next state
        float t0 = tanh_fast(d0[0] + xq0[0]);
        float t1 = tanh_fast(d0[1] + xq0[1]);
        float t2 = tanh_fast(d0[2] + xq0[2]);
        float t3 = tanh_fast(d0[3] + xq0[3]);
        float u0 = tanh_fast(d1[0] + xq1[0]);
        float u1 = tanh_fast(d1[1] + xq1[1]);
        float u2 = tanh_fast(d1[2] + xq1[2]);
        float u3 = tanh_fast(d1[3] + xq1[3]);
        unsigned p01, p23, q01, q23;
        asm("v_cvt_pk_bf16_f32 %0, %1, %2" : "=v"(p01) : "v"(t0), "v"(t1));
        asm("v_cvt_pk_bf16_f32 %0, %1, %2" : "=v"(p23) : "v"(t2), "v"(t3));
        asm("v_cvt_pk_bf16_f32 %0, %1, %2" : "=v"(q01) : "v"(u0), "v"(u1));
        asm("v_cvt_pk_bf16_f32 %0, %1, %2" : "=v"(q23) : "v"(u2), "v"(u3));
        *(uint2*)wa = make_uint2(p01, p23);
        *(uint2*)wb = make_uint2(q01, q23);

        xq0 = xn0; xq1 = xn1;
        __syncthreads();
    };

    // steps 0..509 (even reads buf0, odd reads buf1)
    for (int s = 0; s < 510; s += 2) {
        do_step(rd0, w1a, w1b);
        do_step(rd1, w0a, w0b);
    }
    do_step(rd0, w1a, w1b);        // step 510 (prefetches xp[511])

    // step 511 peeled: read buf1, keep fp32 tanh values for log_softmax
    float vf0[4], vf1[4];
    {
        bf16x8 bf[8];
#pragma unroll
        for (int kk = 0; kk < 8; ++kk)
            bf[kk] = *(const bf16x8*)(rd1 + kk * 512);
        f32x4 c0a = {0.f, 0.f, 0.f, 0.f}, c0b = {0.f, 0.f, 0.f, 0.f};
        f32x4 c1a = {0.f, 0.f, 0.f, 0.f}, c1b = {0.f, 0.f, 0.f, 0.f};
#pragma unroll
        for (int kk = 0; kk < 4; ++kk) {
            c0a = __builtin_amdgcn_mfma_f32_16x16x32_bf16(wfrag[0][kk],     bf[kk],     c0a, 0, 0, 0);
            c1a = __builtin_amdgcn_mfma_f32_16x16x32_bf16(wfrag[1][kk],     bf[kk],     c1a, 0, 0, 0);
            c0b = __builtin_amdgcn_mfma_f32_16x16x32_bf16(wfrag[0][kk + 4], bf[kk + 4], c0b, 0, 0, 0);
            c1b = __builtin_amdgcn_mfma_f32_16x16x32_bf16(wfrag[1][kk + 4], bf[kk + 4], c1b, 0, 0, 0);
        }
        const f32x4 d0 = c0a + c0b;
        const f32x4 d1 = c1a + c1b;
#pragma unroll
        for (int r = 0; r < 4; ++r) {
            vf0[r] = tanh_fast(d0[r] + xq0[r]);
            vf1[r] = tanh_fast(d1[r] + xq1[r]);
        }
    }

    // ---- log_softmax over h=256 for each batch row bl ----
    float m = fmaxf(fmaxf(fmaxf(vf0[0], vf0[1]), fmaxf(vf0[2], vf0[3])),
                    fmaxf(fmaxf(vf1[0], vf1[1]), fmaxf(vf1[2], vf1[3])));
    m = fmaxf(m, __shfl_xor(m, 16));
    m = fmaxf(m, __shfl_xor(m, 32));
    if (lane < 16) sred[wave][bl] = m;
    __syncthreads();
    float mall = sred[0][bl];
#pragma unroll
    for (int w = 1; w < 8; ++w) mall = fmaxf(mall, sred[w][bl]);
    __syncthreads();

    float ss = 0.f;
#pragma unroll
    for (int r = 0; r < 4; ++r)
        ss += __expf(vf0[r] - mall) + __expf(vf1[r] - mall);
    ss += __shfl_xor(ss, 16);
    ss += __shfl_xor(ss, 32);
    if (lane < 16) sred[wave][bl] = ss;
    __syncthreads();
    float tot = sred[0][bl];
#pragma unroll
    for (int w = 1; w < 8; ++w) tot += sred[w][bl];
    const float lse = mall + __logf(tot);

    f32x4 o0, o1;
#pragma unroll
    for (int r = 0; r < 4; ++r) { o0[r] = vf0[r] - lse; o1[r] = vf1[r] - lse; }
    float* op = out + (size_t)(B0 + bl) * H_SZ + wave * 32 + quad * 4;
    *(f32x4*)op        = o0;
    *(f32x4*)(op + 16) = o1;
}

// ---------------------------------------------------------------------------
extern "C" void kernel_launch(void* const* d_in, const int* in_sizes, int n_in,
                              void* d_out, int out_size, void* d_ws, size_t ws_size,
                              hipStream_t stream) {
    const int*   X    = (const int*)  d_in[0];
    const float* emb  = (const float*)d_in[1];
    const float* W_ih = (const float*)d_in[2];
    const float* W_hh = (const float*)d_in[3];
    const float* b_ih = (const float*)d_in[4];
    const float* b_hh = (const float*)d_in[5];
    float* out   = (float*)d_out;
    float* xproj = (float*)d_ws;   // S*B*H fp32 = 134.2 MB

    embed_proj_kernel<<<dim3((S_LEN * B_SZ) / K1_ROWS), 256, 0, stream>>>(
        X, emb, W_ih, b_ih, b_hh, xproj);

    rnn_scan_kernel<<<dim3(B_SZ / 16), 512, 0, stream>>>(xproj, W_hh, out);
}

// Round 2
// 464.125 us; speedup vs baseline: 1.5361x; 1.0584x over previous
//
#include <hip/hip_runtime.h>
#include <math.h>

// Problem constants: S=512, B=256, V=100000, E=128, H=256
#define S_LEN 512
#define B_SZ  256
#define E_SZ  128
#define H_SZ  256

typedef __attribute__((ext_vector_type(8))) short bf16x8;
typedef __attribute__((ext_vector_type(4))) short bf16x4;
typedef __attribute__((ext_vector_type(4))) float f32x4;

__device__ __forceinline__ short f2bf(float f) {
    union { float f; unsigned u; } v; v.f = f;
    unsigned r = v.u + 0x7FFFu + ((v.u >> 16) & 1u);   // RNE
    return (short)(r >> 16);
}
__device__ __forceinline__ float bf2f(short h) {
    union { unsigned u; float f; } c;
    c.u = ((unsigned)(unsigned short)h) << 16;
    return c.f;
}

// tanh(v) = 1 - 2/(exp(2v)+1); v_rcp_f32 (~1 ulp) far below bf16 state noise.
__device__ __forceinline__ float tanh_fast(float v) {
    float e = __expf(2.f * v);
    return 1.f - 2.f * __builtin_amdgcn_rcpf(e + 1.f);
}

// ---------------------------------------------------------------------------
// Kernel 1 (v2): embedding gather + input projection via bf16 MFMA with
// hi/lo split (xp = Ah*Wh + Ah*Wl + Al*Wh -> fp32-level accuracy).
// Block: 256 threads = 4 waves, 64 rows x full H=256.
//  - emb tile staged in LDS in B-fragment-linear layout (hi + lo), 32KB.
//  - wave owns 64 h (4 m-tiles, 2 passes of 2) x 4 n-tiles (64 rows).
//  - Fragment mapping identical to the harness-verified scan kernel.
// ---------------------------------------------------------------------------
__global__ __launch_bounds__(256, 2) void embed_proj_mfma(
    const int*   __restrict__ X,
    const float* __restrict__ emb,
    const float* __restrict__ W_ih,
    const float* __restrict__ b_ih,
    const float* __restrict__ b_hh,
    float*       __restrict__ xproj)
{
    __shared__ int   toks[64];
    __shared__ short BtH[4][4][64][8];   // [ntile][kk][lane][j] hi, 16KB
    __shared__ short BtL[4][4][64][8];   // lo, 16KB

    const int tid  = threadIdx.x;
    const int wave = tid >> 6;           // 0..3
    const int lane = tid & 63;
    const int bl   = lane & 15;
    const int quad = lane >> 4;
    const size_t row0 = (size_t)blockIdx.x * 64;

    if (tid < 64) toks[tid] = X[row0 + tid];
    __syncthreads();

    // ---- stage emb tile (hi/lo bf16) into B-frag-linear LDS ----
    {
        const int r  = tid >> 2;         // 0..63 row
        const int kk = tid & 3;          // k-chunk of 32
        const float* ep = emb + (size_t)toks[r] * E_SZ + kk * 32;
#pragma unroll
        for (int q = 0; q < 4; ++q) {
            float4 a = *(const float4*)(ep + q * 8);
            float4 b = *(const float4*)(ep + q * 8 + 4);
            float v[8] = {a.x, a.y, a.z, a.w, b.x, b.y, b.z, b.w};
            bf16x8 fh, fl;
#pragma unroll
            for (int j = 0; j < 8; ++j) {
                short h = f2bf(v[j]);
                fh[j] = h;
                fl[j] = f2bf(v[j] - bf2f(h));
            }
            *(bf16x8*)&BtH[r >> 4][kk][q * 16 + (r & 15)][0] = fh;
            *(bf16x8*)&BtL[r >> 4][kk][q * 16 + (r & 15)][0] = fl;
        }
    }
    __syncthreads();

    // ---- compute: 2 passes x 2 m-tiles; D[m=h][n=row] = W_ih * Emb^T ----
#pragma unroll
    for (int mp = 0; mp < 2; ++mp) {
        bf16x8 wh[2][4], wl[2][4];
#pragma unroll
        for (int i = 0; i < 2; ++i) {
            const int h = wave * 64 + (mp * 2 + i) * 16 + bl;
#pragma unroll
            for (int kk = 0; kk < 4; ++kk) {
                const float* wp = W_ih + (size_t)h * E_SZ + kk * 32 + quad * 8;
                float4 a = *(const float4*)wp;
                float4 b = *(const float4*)(wp + 4);
                float v[8] = {a.x, a.y, a.z, a.w, b.x, b.y, b.z, b.w};
                bf16x8 fh, fl;
#pragma unroll
                for (int j = 0; j < 8; ++j) {
                    short hh = f2bf(v[j]);
                    fh[j] = hh;
                    fl[j] = f2bf(v[j] - bf2f(hh));
                }
                wh[i][kk] = fh; wl[i][kk] = fl;
            }
        }

        f32x4 acc[2][4];
#pragma unroll
        for (int i = 0; i < 2; ++i)
#pragma unroll
            for (int nt = 0; nt < 4; ++nt) acc[i][nt] = (f32x4){0.f, 0.f, 0.f, 0.f};

#pragma unroll
        for (int kk = 0; kk < 4; ++kk) {
            bf16x8 bh[4], blo[4];
#pragma unroll
            for (int nt = 0; nt < 4; ++nt) {
                bh[nt]  = *(const bf16x8*)&BtH[nt][kk][lane][0];
                blo[nt] = *(const bf16x8*)&BtL[nt][kk][lane][0];
            }
#pragma unroll
            for (int i = 0; i < 2; ++i)
#pragma unroll
                for (int nt = 0; nt < 4; ++nt) {
                    f32x4 a = acc[i][nt];
                    a = __builtin_amdgcn_mfma_f32_16x16x32_bf16(wh[i][kk], bh[nt],  a, 0, 0, 0);
                    a = __builtin_amdgcn_mfma_f32_16x16x32_bf16(wh[i][kk], blo[nt], a, 0, 0, 0);
                    a = __builtin_amdgcn_mfma_f32_16x16x32_bf16(wl[i][kk], bh[nt],  a, 0, 0, 0);
                    acc[i][nt] = a;
                }
        }

        // epilogue: bias + store. lane holds col=n (row nt*16+bl), rows h=quad*4+r
#pragma unroll
        for (int i = 0; i < 2; ++i) {
            const int hb = wave * 64 + (mp * 2 + i) * 16 + quad * 4;
            float4 bi = *(const float4*)&b_ih[hb];
            float4 bh4 = *(const float4*)&b_hh[hb];
#pragma unroll
            for (int nt = 0; nt < 4; ++nt) {
                f32x4 o = acc[i][nt];
                o[0] += bi.x + bh4.x; o[1] += bi.y + bh4.y;
                o[2] += bi.z + bh4.z; o[3] += bi.w + bh4.w;
                *(f32x4*)&xproj[(row0 + nt * 16 + bl) * H_SZ + hb] = o;
            }
        }
    }
}

// ---------------------------------------------------------------------------
// Kernel 2 (v3): MFMA recurrent scan + log_softmax.
//  Changes vs v2:
//  - raw s_barrier + explicit lgkmcnt(0) instead of __syncthreads(): the
//    compiler's vmcnt(0) drain before s_barrier was serializing the xp
//    global prefetch (~L3/HBM latency) into every step.
//  - xp prefetch distance 2 (two register sets, loads issued 2 steps
//    before use; waits land at the consuming epilogue, fully covered).
// ---------------------------------------------------------------------------
__global__ __launch_bounds__(512) void rnn_scan_kernel(
    const float* __restrict__ xproj,
    const float* __restrict__ W_hh,
    float*       __restrict__ out)
{
    const int tid  = threadIdx.x;
    const int wave = tid >> 6;      // 0..7
    const int lane = tid & 63;
    const int bl   = lane & 15;     // batch within block
    const int quad = lane >> 4;     // 0..3
    const int B0   = blockIdx.x * 16;

    __shared__ short HB[2][8][64][8];   // 2 x 8KB state buffers
    __shared__ float sred[8][16];

    // ---- A-operand: W_hh fragments, constant through the scan ----
    bf16x8 wfrag[2][8];
#pragma unroll
    for (int mt = 0; mt < 2; ++mt) {
        const int h = wave * 32 + mt * 16 + bl;
#pragma unroll
        for (int kk = 0; kk < 8; ++kk) {
            const float* wp = W_hh + (size_t)h * H_SZ + kk * 32 + quad * 8;
            float4 x0 = *(const float4*)wp;
            float4 x1 = *(const float4*)(wp + 4);
            bf16x8 f;
            f[0] = f2bf(x0.x); f[1] = f2bf(x0.y); f[2] = f2bf(x0.z); f[3] = f2bf(x0.w);
            f[4] = f2bf(x1.x); f[5] = f2bf(x1.y); f[6] = f2bf(x1.z); f[7] = f2bf(x1.w);
            wfrag[mt][kk] = f;
        }
    }

    short* const hb0 = &HB[0][0][0][0];
    short* const hb1 = &HB[1][0][0][0];

    ((int4*)hb0)[tid] = make_int4(0, 0, 0, 0);   // zero initial state

    const short* rd0 = hb0 + lane * 8;
    const short* rd1 = hb1 + lane * 8;

    // write slots (see v2 derivation): h -> (h>>5)*512 + ((h>>3)&3)*128 + bl*8 + (h&7)
    const int wo0 = wave * 512 + (quad >> 1) * 128 + bl * 8 + (quad & 1) * 4;
    const int wo1 = wo0 + 256;
    short* w0a = hb0 + wo0; short* w0b = hb0 + wo1;
    short* w1a = hb1 + wo0; short* w1b = hb1 + wo1;

    const size_t stp = (size_t)B_SZ * H_SZ;
    const float* xpb = xproj + (size_t)(B0 + bl) * H_SZ + wave * 32 + quad * 4;

    // distance-2 prefetch register sets
    f32x4 xA0 = *(const f32x4*)(xpb);
    f32x4 xA1 = *(const f32x4*)(xpb + 16);
    f32x4 xB0 = *(const f32x4*)(xpb + stp);
    f32x4 xB1 = *(const f32x4*)(xpb + stp + 16);

    __syncthreads();

    float vf0[4], vf1[4];

    auto do_step = [&](const short* rd, short* wa, short* wb,
                       f32x4& x0, f32x4& x1, const float* pf) {
        // B-fragments: 8 x ds_read_b128, conflict-free contiguous
        bf16x8 bf[8];
#pragma unroll
        for (int kk = 0; kk < 8; ++kk)
            bf[kk] = *(const bf16x8*)(rd + kk * 512);

        // 4 independent MFMA chains of 4 (2 m-tiles x 2 k-halves)
        f32x4 c0a = {0.f, 0.f, 0.f, 0.f}, c0b = {0.f, 0.f, 0.f, 0.f};
        f32x4 c1a = {0.f, 0.f, 0.f, 0.f}, c1b = {0.f, 0.f, 0.f, 0.f};
#pragma unroll
        for (int kk = 0; kk < 4; ++kk) {
            c0a = __builtin_amdgcn_mfma_f32_16x16x32_bf16(wfrag[0][kk],     bf[kk],     c0a, 0, 0, 0);
            c1a = __builtin_amdgcn_mfma_f32_16x16x32_bf16(wfrag[1][kk],     bf[kk],     c1a, 0, 0, 0);
            c0b = __builtin_amdgcn_mfma_f32_16x16x32_bf16(wfrag[0][kk + 4], bf[kk + 4], c0b, 0, 0, 0);
            c1b = __builtin_amdgcn_mfma_f32_16x16x32_bf16(wfrag[1][kk + 4], bf[kk + 4], c1b, 0, 0, 0);
        }
        const f32x4 d0 = c0a + c0b;
        const f32x4 d1 = c1a + c1b;

        // epilogue: v = D + xp, tanh, pack bf16, store next state
        float t0 = tanh_fast(d0[0] + x0[0]);
        float t1 = tanh_fast(d0[1] + x0[1]);
        float t2 = tanh_fast(d0[2] + x0[2]);
        float t3 = tanh_fast(d0[3] + x0[3]);
        float u0 = tanh_fast(d1[0] + x1[0]);
        float u1 = tanh_fast(d1[1] + x1[1]);
        float u2 = tanh_fast(d1[2] + x1[2]);
        float u3 = tanh_fast(d1[3] + x1[3]);
        unsigned p01, p23, q01, q23;
        asm("v_cvt_pk_bf16_f32 %0, %1, %2" : "=v"(p01) : "v"(t0), "v"(t1));
        asm("v_cvt_pk_bf16_f32 %0, %1, %2" : "=v"(p23) : "v"(t2), "v"(t3));
        asm("v_cvt_pk_bf16_f32 %0, %1, %2" : "=v"(q01) : "v"(u0), "v"(u1));
        asm("v_cvt_pk_bf16_f32 %0, %1, %2" : "=v"(q23) : "v"(u2), "v"(u3));
        *(uint2*)wa = make_uint2(p01, p23);
        *(uint2*)wb = make_uint2(q01, q23);

        // issue prefetch for step s+2 into the registers just consumed
        x0 = *(const f32x4*)pf;
        x1 = *(const f32x4*)(pf + 16);

        // own LDS ops done -> barrier. NO vmcnt drain: prefetch stays in flight.
        asm volatile("s_waitcnt lgkmcnt(0)" ::: "memory");
        __builtin_amdgcn_sched_barrier(0);
        __builtin_amdgcn_s_barrier();
    };

    const float* pfA = xpb + 2 * stp;
    const float* pfB = xpb + 3 * stp;
    for (int s = 0; s < 510; s += 2) {
        do_step(rd0, w1a, w1b, xA0, xA1, pfA);    // even step s
        do_step(rd1, w0a, w0b, xB0, xB1, pfB);    // odd step s+1
        pfA += 2 * stp; pfB += 2 * stp;
        if (pfA > xpb + 511 * stp) pfA = xpb;     // clamp (dummy in-bounds read)
        if (pfB > xpb + 511 * stp) pfB = xpb;
    }
    do_step(rd0, w1a, w1b, xA0, xA1, xpb);        // step 510

    // step 511 peeled: read buf1, keep fp32 tanh values for log_softmax
    {
        bf16x8 bf[8];
#pragma unroll
        for (int kk = 0; kk < 8; ++kk)
            bf[kk] = *(const bf16x8*)(rd1 + kk * 512);
        f32x4 c0a = {0.f, 0.f, 0.f, 0.f}, c0b = {0.f, 0.f, 0.f, 0.f};
        f32x4 c1a = {0.f, 0.f, 0.f, 0.f}, c1b = {0.f, 0.f, 0.f, 0.f};
#pragma unroll
        for (int kk = 0; kk < 4; ++kk) {
            c0a = __builtin_amdgcn_mfma_f32_16x16x32_bf16(wfrag[0][kk],     bf[kk],     c0a, 0, 0, 0);
            c1a = __builtin_amdgcn_mfma_f32_16x16x32_bf16(wfrag[1][kk],     bf[kk],     c1a, 0, 0, 0);
            c0b = __builtin_amdgcn_mfma_f32_16x16x32_bf16(wfrag[0][kk + 4], bf[kk + 4], c0b, 0, 0, 0);
            c1b = __builtin_amdgcn_mfma_f32_16x16x32_bf16(wfrag[1][kk + 4], bf[kk + 4], c1b, 0, 0, 0);
        }
        const f32x4 d0 = c0a + c0b;
        const f32x4 d1 = c1a + c1b;
#pragma unroll
        for (int r = 0; r < 4; ++r) {
            vf0[r] = tanh_fast(d0[r] + xB0[r]);
            vf1[r] = tanh_fast(d1[r] + xB1[r]);
        }
    }

    // ---- log_softmax over h=256 for each batch row bl ----
    float m = fmaxf(fmaxf(fmaxf(vf0[0], vf0[1]), fmaxf(vf0[2], vf0[3])),
                    fmaxf(fmaxf(vf1[0], vf1[1]), fmaxf(vf1[2], vf1[3])));
    m = fmaxf(m, __shfl_xor(m, 16));
    m = fmaxf(m, __shfl_xor(m, 32));
    if (lane < 16) sred[wave][bl] = m;
    __syncthreads();
    float mall = sred[0][bl];
#pragma unroll
    for (int w = 1; w < 8; ++w) mall = fmaxf(mall, sred[w][bl]);
    __syncthreads();

    float ss = 0.f;
#pragma unroll
    for (int r = 0; r < 4; ++r)
        ss += __expf(vf0[r] - mall) + __expf(vf1[r] - mall);
    ss += __shfl_xor(ss, 16);
    ss += __shfl_xor(ss, 32);
    if (lane < 16) sred[wave][bl] = ss;
    __syncthreads();
    float tot = sred[0][bl];
#pragma unroll
    for (int w = 1; w < 8; ++w) tot += sred[w][bl];
    const float lse = mall + __logf(tot);

    f32x4 o0, o1;
#pragma unroll
    for (int r = 0; r < 4; ++r) { o0[r] = vf0[r] - lse; o1[r] = vf1[r] - lse; }
    float* op = out + (size_t)(B0 + bl) * H_SZ + wave * 32 + quad * 4;
    *(f32x4*)op        = o0;
    *(f32x4*)(op + 16) = o1;
}

// ---------------------------------------------------------------------------
extern "C" void kernel_launch(void* const* d_in, const int* in_sizes, int n_in,
                              void* d_out, int out_size, void* d_ws, size_t ws_size,
                              hipStream_t stream) {
    const int*   X    = (const int*)  d_in[0];
    const float* emb  = (const float*)d_in[1];
    const float* W_ih = (const float*)d_in[2];
    const float* W_hh = (const float*)d_in[3];
    const float* b_ih = (const float*)d_in[4];
    const float* b_hh = (const float*)d_in[5];
    float* out   = (float*)d_out;
    float* xproj = (float*)d_ws;   // S*B*H fp32 = 134.2 MB

    embed_proj_mfma<<<dim3((S_LEN * B_SZ) / 64), 256, 0, stream>>>(
        X, emb, W_ih, b_ih, b_hh, xproj);

    rnn_scan_kernel<<<dim3(B_SZ / 16), 512, 0, stream>>>(xproj, W_hh, out);
}